// Round 4
// baseline (140.113 us; speedup 1.0000x reference)
//
#include <hip/hip_runtime.h>
#include <hip/hip_bf16.h>

#define NHEAD 4
#define FIN   768
#define FOUT  64
#define BSZ   4
#define NSEQ  2048
#define BH    (BSZ*NHEAD)
#define LOG2E 1.44269504088896f

typedef __attribute__((ext_vector_type(8)))  short bf16x8;   // MFMA A/B frag
typedef __attribute__((ext_vector_type(16))) float f32x16;   // MFMA 32x32 C/D
typedef __attribute__((ext_vector_type(8)))  unsigned short u16x8;
typedef __attribute__((ext_vector_type(4)))  unsigned short u16x4;
typedef __attribute__((ext_vector_type(4)))  unsigned u32x4;

__device__ __forceinline__ unsigned short f2bf(float f){
  unsigned b = __float_as_uint(f);
  return (unsigned short)((b + 0x7fffu + ((b >> 16) & 1u)) >> 16);
}
__device__ __forceinline__ float fexp2(float x){
#if __has_builtin(__builtin_amdgcn_exp2f)
  return __builtin_amdgcn_exp2f(x);
#else
  return exp2f(x);
#endif
}
__device__ __forceinline__ unsigned pkbf(float lo, float hi){
#if __has_builtin(__builtin_amdgcn_cvt_pk_bf16_f32)
  typedef __attribute__((ext_vector_type(2))) __bf16 bf2;
  union { bf2 v; unsigned u; } cv;
  cv.v = __builtin_amdgcn_cvt_pk_bf16_f32(lo, hi);
  return cv.u;
#else
  return (unsigned)f2bf(lo) | ((unsigned)f2bf(hi) << 16);
#endif
}
// fast tanh via exp2: tanh(v) = 1 - 2/(exp2(2*log2e*v)+1). |err| ~1e-7.
__device__ __forceinline__ float fast_tanh(float v){
  const float e = fexp2(v * (2.0f*LOG2E));
#if __has_builtin(__builtin_amdgcn_rcpf)
  return 1.0f - 2.0f*__builtin_amdgcn_rcpf(e + 1.0f);
#else
  return 1.0f - 2.0f/(e + 1.0f);
#endif
}

// ---------------------------------------------------------------------------
// Kernel A v4: round-0 structure + (a) prefetch loads issued BEFORE the
// barrier, (b) raw s_barrier with lgkmcnt(0)-only drain so global loads stay
// in flight across it (AITER pattern; plain __syncthreads drains vmcnt(0)
// and serializes the L3 load latency into every iter), (c) fast_tanh.
// Launched TWICE this round as an idempotence-safe duration probe.
// ---------------------------------------------------------------------------
__global__ __launch_bounds__(512, 2) void k_hprime(
    const float* __restrict__ h, const float* __restrict__ w,
    const float* __restrict__ a_src, const float* __restrict__ a_dst,
    unsigned short* __restrict__ hpz2, float* __restrict__ srcv,
    float* __restrict__ dstv)
{
  __shared__ __align__(16) char smem[65536];
  // A0@0, A1@16384, B0@32768, B1@49152
  // epilogue overlays: scratch@0 (16K), psumS@16384, psumD@16896, Tt@32768 (8K)
  float* psumS = (float*)(smem + 16384);
  float* psumD = (float*)(smem + 16896);
  char*  Tt    = smem + 32768;

  const int tid  = threadIdx.x;
  const int bid  = blockIdx.x;
  const int bh1  = (bid & 7) | (((bid >> 3) & 1) << 3);
  const int head = bh1 & 3;
  const int jbase = (bid >> 4) << 6;                 // within-sequence row base
  const int i0a   = (bh1 >> 2)*NSEQ + jbase;         // global flat row
  const int wave = tid >> 6, lane = tid & 63;
  const int wm = wave & 1, wn = (wave >> 1) & 1, kw = wave >> 2;
  const int l32 = lane & 31, h32 = lane >> 5;

  f32x16 acc = {0,0,0,0,0,0,0,0,0,0,0,0,0,0,0,0};

  // A staging map: row sr, chunk sc (r9-proven)
  const int sr = tid >> 3, sc = tid & 7;
  const float* hA = h + (size_t)(i0a + sr)*FIN + sc*8;
  const int aslot = (sc ^ (sr & 7)) << 4;

  // B staging map: o = lane (coalesced), halves g0 = cc, g1 = cc+8
  const int ob = tid & 63, cc = tid >> 6;
  const float* wsrc = w + (size_t)head*FIN*FOUT + ob;   // + f*64
  const int bslot0 = ((cc & 7) ^ (ob & 7)) << 4;        // half 0 slot

  // prologue: prefetch iter 0
  float4 ra0 = *(const float4*)(hA);
  float4 ra1 = *(const float4*)(hA + 4);
  float4 ra2 = *(const float4*)(hA + 64);
  float4 ra3 = *(const float4*)(hA + 68);
  float rb[16];
  #pragma unroll
  for (int j = 0; j < 8; ++j){
    rb[j]     = wsrc[(size_t)(cc*8 + j)*FOUT];          // g0 = cc   (k 0..63)
    rb[8 + j] = wsrc[(size_t)(64 + cc*8 + j)*FOUT];     // g1 = cc+8 (k 64..127)
  }

  for (int it = 0; it < 6; ++it){
    char* Ab = smem +         (it & 1)*16384;
    char* Bb = smem + 32768 + (it & 1)*16384;
    // pack current regs (consumes ra*/rb)
    u32x4 pk0, pk1;
    pk0[0] = pkbf(ra0.x, ra0.y); pk0[1] = pkbf(ra0.z, ra0.w);
    pk0[2] = pkbf(ra1.x, ra1.y); pk0[3] = pkbf(ra1.z, ra1.w);
    pk1[0] = pkbf(ra2.x, ra2.y); pk1[1] = pkbf(ra2.z, ra2.w);
    pk1[2] = pkbf(ra3.x, ra3.y); pk1[3] = pkbf(ra3.z, ra3.w);
    u32x4 qb0, qb1;
    qb0[0] = pkbf(rb[0],  rb[1]);  qb0[1] = pkbf(rb[2],  rb[3]);
    qb0[2] = pkbf(rb[4],  rb[5]);  qb0[3] = pkbf(rb[6],  rb[7]);
    qb1[0] = pkbf(rb[8],  rb[9]);  qb1[1] = pkbf(rb[10], rb[11]);
    qb1[2] = pkbf(rb[12], rb[13]); qb1[3] = pkbf(rb[14], rb[15]);
    // issue next-iter loads EARLY; they stay in flight across the raw barrier
    if (it < 5){
      const float* an = hA + (it+1)*128;
      ra0 = *(const float4*)(an);      ra1 = *(const float4*)(an + 4);
      ra2 = *(const float4*)(an + 64); ra3 = *(const float4*)(an + 68);
      const float* wn_ = wsrc + (size_t)(it+1)*128*FOUT;
      #pragma unroll
      for (int j = 0; j < 8; ++j){
        rb[j]     = wn_[(size_t)(cc*8 + j)*FOUT];
        rb[8 + j] = wn_[(size_t)(64 + cc*8 + j)*FOUT];
      }
    }
    *(u32x4*)(Ab + sr*256 + aslot)        = pk0;
    *(u32x4*)(Ab + sr*256 + 128 + aslot)  = pk1;
    *(u32x4*)(Bb + ob*256 +       bslot0) = qb0;
    *(u32x4*)(Bb + ob*256 + 128 + bslot0) = qb1;
    // LDS-only drain + raw barrier: global prefetch stays outstanding
    asm volatile("s_waitcnt lgkmcnt(0)" ::: "memory");
    __builtin_amdgcn_s_barrier();
    __builtin_amdgcn_sched_barrier(0);
    #pragma unroll
    for (int s = 0; s < 4; ++s){
      const int slot = (((s*2 + h32) ^ (l32 & 7)) << 4);
      bf16x8 av = *(const bf16x8*)(Ab + (wm*32 + l32)*256 + kw*128 + slot);
      bf16x8 bv = *(const bf16x8*)(Bb + (wn*32 + l32)*256 + kw*128 + slot);
      acc = __builtin_amdgcn_mfma_f32_32x32x16_bf16(av, bv, acc, 0, 0, 0);
    }
  }

  // kw-merge via scratch@0 (A0 region; iter-5 MFMA read A1/B1 - disjoint)
  if (kw == 1) *(f32x16*)(smem + (size_t)((wave & 3)*64 + lane)*64) = acc;
  __syncthreads();
  if (kw == 0){
    acc += *(const f32x16*)(smem + (size_t)((wave & 3)*64 + lane)*64);
    const float as = a_src[head*64 + wn*32 + l32];
    const float ad = a_dst[head*64 + wn*32 + l32];
    #pragma unroll
    for (int rb2 = 0; rb2 < 4; ++rb2){
      const int jb = wm*32 + rb2*8 + h32*4;
      u16x4 c4;
      #pragma unroll
      for (int q = 0; q < 4; ++q){
        const float v = acc[rb2*4 + q];
        c4[q] = f2bf(v);
        const float t = fast_tanh(v);
        float ps = t*as, pd = t*ad;
        ps += __shfl_xor(ps, 1);  ps += __shfl_xor(ps, 2);  ps += __shfl_xor(ps, 4);
        ps += __shfl_xor(ps, 8);  ps += __shfl_xor(ps, 16);
        pd += __shfl_xor(pd, 1);  pd += __shfl_xor(pd, 2);  pd += __shfl_xor(pd, 4);
        pd += __shfl_xor(pd, 8);  pd += __shfl_xor(pd, 16);
        if (l32 == 0){
          psumS[(jb + q)*2 + wn] = ps;
          psumD[(jb + q)*2 + wn] = pd;
        }
      }
      const int orow = wn*32 + l32;
      const int slot = ((jb >> 3) & 7) ^ (orow & 7);
      *(u16x4*)(Tt + orow*128 + slot*16 + (jb & 7)*2) = c4;
    }
  }
  __syncthreads();

  {
    const int o = tid & 63, c = tid >> 6;
    u16x8 val = *(const u16x8*)(Tt + o*128 + ((c ^ (o & 7)) << 4));
    *(u16x8*)((char*)hpz2 + ((size_t)(bh1*256 + (jbase >> 3) + c)*64 + o)*16) = val;
  }
  if (tid < 64){
    // log2-domain pre-scale; NO max subtraction needed downstream (bounded
    // inputs: |s|,|d| <= ~28.1 in log2 units -> exp2 range fp32-safe)
    srcv[(size_t)bh1*NSEQ + jbase + tid] = (psumS[tid*2] + psumS[tid*2 + 1]) * LOG2E;
    dstv[(size_t)bh1*NSEQ + jbase + tid] = (psumD[tid*2] + psumD[tid*2 + 1]) * LOG2E;
  }
}

// ---------------------------------------------------------------------------
// Kernel B v2 (byte-identical to round 3): barrier-free main loop, direct-
// global B fragments (L2-resident hpz2), register double-buffered.
// ---------------------------------------------------------------------------
__global__ __launch_bounds__(512, 4) void k_attn(
    const unsigned short* __restrict__ hpz2, const float* __restrict__ srcv,
    const float* __restrict__ dstv, const float* __restrict__ bias,
    float* __restrict__ out)
{
  __shared__ __align__(16) char smem[33792];   // ob@0 (32 KB), Lbuf@32768
  float* Lbuf = (float*)(smem + 32768);        // [8][32]

  const int tid = threadIdx.x;
  const int bid = blockIdx.x;
  const int bh  = (bid & 7) | (((bid >> 3) & 1) << 3);
  const int i0  = (bid >> 4) << 6;
  const int wave = tid >> 6, lane = tid & 63;
  const int wm = wave & 1, jw = wave >> 1;
  const int l32 = lane & 31, h32 = lane >> 5;

  const float s2 = srcv[(size_t)bh*NSEQ + i0 + wm*32 + l32];
  const float u_ = s2;                 // lrelu(s+d) = max(u_+d, 0.2d+v_)
  const float v_ = 0.2f*s2;

  // direct-global B fragments: unit(w,Jl,half,l32) = w*1024 + Jl*64 + half*32 + l32
  const u16x8* gp = (const u16x8*)((const char*)hpz2 + (size_t)bh*256*64*16);
  const u16x8* tp = gp + ((jw*4 + h32)*64 + l32);      // Jl0 row; Jl1 = +128
  const float* dS = dstv + (size_t)bh*NSEQ + (jw*4 + h32)*8;  // Jl0 j-chunk; Jl1 = +16

  f32x16 accO0 = {0,0,0,0,0,0,0,0,0,0,0,0,0,0,0,0};
  f32x16 accO1 = {0,0,0,0,0,0,0,0,0,0,0,0,0,0,0,0};
  float lpart = 0.f;

  u16x8 c0 = tp[0], c1 = tp[32], c2 = tp[128], c3 = tp[160];

  for (int w = 0; w < 16; ++w){
    u16x8 n0, n1, n2, n3;
    if (w < 15){
      const u16x8* np = tp + 1024;
      n0 = np[0]; n1 = np[32]; n2 = np[128]; n3 = np[160];
    }
    float4 d0 = *(const float4*)(dS);
    float4 d1 = *(const float4*)(dS + 4);
    float4 d2 = *(const float4*)(dS + 16);
    float4 d3 = *(const float4*)(dS + 20);
    // stl0 (rows jw*4 + h32)
    {
      float e0 = fexp2(fmaxf(u_ + d0.x, fmaf(0.2f, d0.x, v_)));
      float e1 = fexp2(fmaxf(u_ + d0.y, fmaf(0.2f, d0.y, v_)));
      float e2 = fexp2(fmaxf(u_ + d0.z, fmaf(0.2f, d0.z, v_)));
      float e3 = fexp2(fmaxf(u_ + d0.w, fmaf(0.2f, d0.w, v_)));
      float e4 = fexp2(fmaxf(u_ + d1.x, fmaf(0.2f, d1.x, v_)));
      float e5 = fexp2(fmaxf(u_ + d1.y, fmaf(0.2f, d1.y, v_)));
      float e6 = fexp2(fmaxf(u_ + d1.z, fmaf(0.2f, d1.z, v_)));
      float e7 = fexp2(fmaxf(u_ + d1.w, fmaf(0.2f, d1.w, v_)));
      lpart += ((e0+e1)+(e2+e3)) + ((e4+e5)+(e6+e7));
      u32x4 pk;
      pk[0] = pkbf(e0, e1); pk[1] = pkbf(e2, e3);
      pk[2] = pkbf(e4, e5); pk[3] = pkbf(e6, e7);
      const bf16x8 pA = __builtin_bit_cast(bf16x8, pk);
      accO0 = __builtin_amdgcn_mfma_f32_32x32x16_bf16(pA, c0, accO0, 0, 0, 0);
      accO1 = __builtin_amdgcn_mfma_f32_32x32x16_bf16(pA, c1, accO1, 0, 0, 0);
    }
    // stl1 (rows jw*4 + 2 + h32)
    {
      float e0 = fexp2(fmaxf(u_ + d2.x, fmaf(0.2f, d2.x, v_)));
      float e1 = fexp2(fmaxf(u_ + d2.y, fmaf(0.2f, d2.y, v_)));
      float e2 = fexp2(fmaxf(u_ + d2.z, fmaf(0.2f, d2.z, v_)));
      float e3 = fexp2(fmaxf(u_ + d2.w, fmaf(0.2f, d2.w, v_)));
      float e4 = fexp2(fmaxf(u_ + d3.x, fmaf(0.2f, d3.x, v_)));
      float e5 = fexp2(fmaxf(u_ + d3.y, fmaf(0.2f, d3.y, v_)));
      float e6 = fexp2(fmaxf(u_ + d3.z, fmaf(0.2f, d3.z, v_)));
      float e7 = fexp2(fmaxf(u_ + d3.w, fmaf(0.2f, d3.w, v_)));
      lpart += ((e0+e1)+(e2+e3)) + ((e4+e5)+(e6+e7));
      u32x4 pk;
      pk[0] = pkbf(e0, e1); pk[1] = pkbf(e2, e3);
      pk[2] = pkbf(e4, e5); pk[3] = pkbf(e6, e7);
      const bf16x8 pA = __builtin_bit_cast(bf16x8, pk);
      accO0 = __builtin_amdgcn_mfma_f32_32x32x16_bf16(pA, c2, accO0, 0, 0, 0);
      accO1 = __builtin_amdgcn_mfma_f32_32x32x16_bf16(pA, c3, accO1, 0, 0, 0);
    }
    tp += 1024; dS += 128;
    c0 = n0; c1 = n1; c2 = n2; c3 = n3;
  }

  lpart += __shfl_xor(lpart, 32);
  if (lane < 32) Lbuf[(wm*4 + jw)*32 + l32] = lpart;

  const float4 bia = *(const float4*)(bias + (tid & 15)*4);
  #pragma unroll
  for (int ph = 0; ph < 2; ++ph){
    __syncthreads();
    if (wm == ph){
      float* ob = (float*)smem;            // [jw][m 32][o 64] fp32 = 32 KB
      #pragma unroll
      for (int reg = 0; reg < 16; ++reg){
        const int m = (reg & 3) + 8*(reg >> 2) + 4*h32;
        ob[(jw*32 + m)*64 +      l32] = accO0[reg];
        ob[(jw*32 + m)*64 + 32 + l32] = accO1[reg];
      }
    }
    __syncthreads();
    {
      const int i = tid >> 4, o4 = (tid & 15)*4;
      const float* ob = (const float*)smem;
      float4 v0 = *(const float4*)(ob + (0*32 + i)*64 + o4);
      float4 v1 = *(const float4*)(ob + (1*32 + i)*64 + o4);
      float4 v2 = *(const float4*)(ob + (2*32 + i)*64 + o4);
      float4 v3 = *(const float4*)(ob + (3*32 + i)*64 + o4);
      const float l = Lbuf[(ph*4+0)*32 + i] + Lbuf[(ph*4+1)*32 + i]
                    + Lbuf[(ph*4+2)*32 + i] + Lbuf[(ph*4+3)*32 + i];
      const float r = 1.f / l;
      float4 res;
      res.x = (v0.x + v1.x + v2.x + v3.x)*r + bia.x;
      res.y = (v0.y + v1.y + v2.y + v3.y)*r + bia.y;
      res.z = (v0.z + v1.z + v2.z + v3.z)*r + bia.z;
      res.w = (v0.w + v1.w + v2.w + v3.w)*r + bia.w;
      *(float4*)(out + ((size_t)bh*NSEQ + i0 + ph*32 + i)*64 + o4) = res;
    }
  }
}

// ---------------------------------------------------------------------------
extern "C" void kernel_launch(void* const* d_in, const int* in_sizes, int n_in,
                              void* d_out, int out_size, void* d_ws, size_t ws_size,
                              hipStream_t stream)
{
  const float* h     = (const float*)d_in[0];
  const float* w     = (const float*)d_in[1];
  const float* a_src = (const float*)d_in[2];
  const float* a_dst = (const float*)d_in[3];
  const float* bias  = (const float*)d_in[4];
  float* out = (float*)d_out;

  char* ws = (char*)d_ws;
  unsigned short* hpz2 = (unsigned short*)ws;                 // 4 MB bf16 chunk-linear
  float* srcv = (float*)(ws + (4u<<20));                      // 128 KB (log2-scaled)
  float* dstv = (float*)(ws + (4u<<20) + (128u<<10));         // 128 KB (log2-scaled)

  // PROBE: k_hprime is idempotent; second launch measures H_warm directly
  // (dur delta vs round 3 = H_warm + one launch gap).
  k_hprime<<<512, 512, 0, stream>>>(h, w, a_src, a_dst, hpz2, srcv, dstv);
  k_hprime<<<512, 512, 0, stream>>>(h, w, a_src, a_dst, hpz2, srcv, dstv);
  k_attn<<<512, 512, 0, stream>>>(hpz2, srcv, dstv, bias, out);
}

// Round 5
// 116.622 us; speedup vs baseline: 1.2014x; 1.2014x over previous
//
#include <hip/hip_runtime.h>
#include <hip/hip_bf16.h>

#define NHEAD 4
#define FIN   768
#define FOUT  64
#define BSZ   4
#define NSEQ  2048
#define BH    (BSZ*NHEAD)
#define LOG2E 1.44269504088896f

typedef __attribute__((ext_vector_type(8)))  short bf16x8;   // MFMA A/B frag
typedef __attribute__((ext_vector_type(16))) float f32x16;   // MFMA 32x32 C/D
typedef __attribute__((ext_vector_type(8)))  unsigned short u16x8;
typedef __attribute__((ext_vector_type(4)))  unsigned short u16x4;
typedef __attribute__((ext_vector_type(4)))  unsigned u32x4;

__device__ __forceinline__ unsigned short f2bf(float f){
  unsigned b = __float_as_uint(f);
  return (unsigned short)((b + 0x7fffu + ((b >> 16) & 1u)) >> 16);
}
__device__ __forceinline__ float fexp2(float x){
#if __has_builtin(__builtin_amdgcn_exp2f)
  return __builtin_amdgcn_exp2f(x);
#else
  return exp2f(x);
#endif
}
__device__ __forceinline__ unsigned pkbf(float lo, float hi){
#if __has_builtin(__builtin_amdgcn_cvt_pk_bf16_f32)
  typedef __attribute__((ext_vector_type(2))) __bf16 bf2;
  union { bf2 v; unsigned u; } cv;
  cv.v = __builtin_amdgcn_cvt_pk_bf16_f32(lo, hi);
  return cv.u;
#else
  return (unsigned)f2bf(lo) | ((unsigned)f2bf(hi) << 16);
#endif
}
// fast tanh via exp2: tanh(v) = 1 - 2/(exp2(2*log2e*v)+1). |err| ~1e-7.
__device__ __forceinline__ float fast_tanh(float v){
  const float e = fexp2(v * (2.0f*LOG2E));
#if __has_builtin(__builtin_amdgcn_rcpf)
  return 1.0f - 2.0f*__builtin_amdgcn_rcpf(e + 1.0f);
#else
  return 1.0f - 2.0f/(e + 1.0f);
#endif
}

// ---------------------------------------------------------------------------
// Kernel A v5: round-4 pipelined structure (early prefetch, lgkmcnt-only
// barrier drain, fast_tanh) + __launch_bounds__(512,4): LDS 64 KB <= 80 KB
// allows 2 blocks/CU -> all 512 blocks co-resident in ONE dispatch round
// (the (512,2) version ran 2 sequential rounds of 256 blocks).
// ---------------------------------------------------------------------------
__global__ __launch_bounds__(512, 4) void k_hprime(
    const float* __restrict__ h, const float* __restrict__ w,
    const float* __restrict__ a_src, const float* __restrict__ a_dst,
    unsigned short* __restrict__ hpz2, float* __restrict__ srcv,
    float* __restrict__ dstv)
{
  __shared__ __align__(16) char smem[65536];
  // A0@0, A1@16384, B0@32768, B1@49152
  // epilogue overlays: scratch@0 (16K), psumS@16384, psumD@16896, Tt@32768 (8K)
  float* psumS = (float*)(smem + 16384);
  float* psumD = (float*)(smem + 16896);
  char*  Tt    = smem + 32768;

  const int tid  = threadIdx.x;
  const int bid  = blockIdx.x;
  const int bh1  = (bid & 7) | (((bid >> 3) & 1) << 3);
  const int head = bh1 & 3;
  const int jbase = (bid >> 4) << 6;                 // within-sequence row base
  const int i0a   = (bh1 >> 2)*NSEQ + jbase;         // global flat row
  const int wave = tid >> 6, lane = tid & 63;
  const int wm = wave & 1, wn = (wave >> 1) & 1, kw = wave >> 2;
  const int l32 = lane & 31, h32 = lane >> 5;

  f32x16 acc = {0,0,0,0,0,0,0,0,0,0,0,0,0,0,0,0};

  // A staging map: row sr, chunk sc (r9-proven)
  const int sr = tid >> 3, sc = tid & 7;
  const float* hA = h + (size_t)(i0a + sr)*FIN + sc*8;
  const int aslot = (sc ^ (sr & 7)) << 4;

  // B staging map: o = lane (coalesced), halves g0 = cc, g1 = cc+8
  const int ob = tid & 63, cc = tid >> 6;
  const float* wsrc = w + (size_t)head*FIN*FOUT + ob;   // + f*64
  const int bslot0 = ((cc & 7) ^ (ob & 7)) << 4;        // half 0 slot

  // prologue: prefetch iter 0
  float4 ra0 = *(const float4*)(hA);
  float4 ra1 = *(const float4*)(hA + 4);
  float4 ra2 = *(const float4*)(hA + 64);
  float4 ra3 = *(const float4*)(hA + 68);
  float rb[16];
  #pragma unroll
  for (int j = 0; j < 8; ++j){
    rb[j]     = wsrc[(size_t)(cc*8 + j)*FOUT];          // g0 = cc   (k 0..63)
    rb[8 + j] = wsrc[(size_t)(64 + cc*8 + j)*FOUT];     // g1 = cc+8 (k 64..127)
  }

  for (int it = 0; it < 6; ++it){
    char* Ab = smem +         (it & 1)*16384;
    char* Bb = smem + 32768 + (it & 1)*16384;
    // pack current regs (consumes ra*/rb)
    u32x4 pk0, pk1;
    pk0[0] = pkbf(ra0.x, ra0.y); pk0[1] = pkbf(ra0.z, ra0.w);
    pk0[2] = pkbf(ra1.x, ra1.y); pk0[3] = pkbf(ra1.z, ra1.w);
    pk1[0] = pkbf(ra2.x, ra2.y); pk1[1] = pkbf(ra2.z, ra2.w);
    pk1[2] = pkbf(ra3.x, ra3.y); pk1[3] = pkbf(ra3.z, ra3.w);
    u32x4 qb0, qb1;
    qb0[0] = pkbf(rb[0],  rb[1]);  qb0[1] = pkbf(rb[2],  rb[3]);
    qb0[2] = pkbf(rb[4],  rb[5]);  qb0[3] = pkbf(rb[6],  rb[7]);
    qb1[0] = pkbf(rb[8],  rb[9]);  qb1[1] = pkbf(rb[10], rb[11]);
    qb1[2] = pkbf(rb[12], rb[13]); qb1[3] = pkbf(rb[14], rb[15]);
    // issue next-iter loads EARLY; they stay in flight across the raw barrier
    if (it < 5){
      const float* an = hA + (it+1)*128;
      ra0 = *(const float4*)(an);      ra1 = *(const float4*)(an + 4);
      ra2 = *(const float4*)(an + 64); ra3 = *(const float4*)(an + 68);
      const float* wn_ = wsrc + (size_t)(it+1)*128*FOUT;
      #pragma unroll
      for (int j = 0; j < 8; ++j){
        rb[j]     = wn_[(size_t)(cc*8 + j)*FOUT];
        rb[8 + j] = wn_[(size_t)(64 + cc*8 + j)*FOUT];
      }
    }
    *(u32x4*)(Ab + sr*256 + aslot)        = pk0;
    *(u32x4*)(Ab + sr*256 + 128 + aslot)  = pk1;
    *(u32x4*)(Bb + ob*256 +       bslot0) = qb0;
    *(u32x4*)(Bb + ob*256 + 128 + bslot0) = qb1;
    // LDS-only drain + raw barrier: global prefetch stays outstanding
    asm volatile("s_waitcnt lgkmcnt(0)" ::: "memory");
    __builtin_amdgcn_s_barrier();
    __builtin_amdgcn_sched_barrier(0);
    #pragma unroll
    for (int s = 0; s < 4; ++s){
      const int slot = (((s*2 + h32) ^ (l32 & 7)) << 4);
      bf16x8 av = *(const bf16x8*)(Ab + (wm*32 + l32)*256 + kw*128 + slot);
      bf16x8 bv = *(const bf16x8*)(Bb + (wn*32 + l32)*256 + kw*128 + slot);
      acc = __builtin_amdgcn_mfma_f32_32x32x16_bf16(av, bv, acc, 0, 0, 0);
    }
  }

  // kw-merge via scratch@0 (A0 region; iter-5 MFMA read A1/B1 - disjoint)
  if (kw == 1) *(f32x16*)(smem + (size_t)((wave & 3)*64 + lane)*64) = acc;
  __syncthreads();
  if (kw == 0){
    acc += *(const f32x16*)(smem + (size_t)((wave & 3)*64 + lane)*64);
    const float as = a_src[head*64 + wn*32 + l32];
    const float ad = a_dst[head*64 + wn*32 + l32];
    #pragma unroll
    for (int rb2 = 0; rb2 < 4; ++rb2){
      const int jb = wm*32 + rb2*8 + h32*4;
      u16x4 c4;
      #pragma unroll
      for (int q = 0; q < 4; ++q){
        const float v = acc[rb2*4 + q];
        c4[q] = f2bf(v);
        const float t = fast_tanh(v);
        float ps = t*as, pd = t*ad;
        ps += __shfl_xor(ps, 1);  ps += __shfl_xor(ps, 2);  ps += __shfl_xor(ps, 4);
        ps += __shfl_xor(ps, 8);  ps += __shfl_xor(ps, 16);
        pd += __shfl_xor(pd, 1);  pd += __shfl_xor(pd, 2);  pd += __shfl_xor(pd, 4);
        pd += __shfl_xor(pd, 8);  pd += __shfl_xor(pd, 16);
        if (l32 == 0){
          psumS[(jb + q)*2 + wn] = ps;
          psumD[(jb + q)*2 + wn] = pd;
        }
      }
      const int orow = wn*32 + l32;
      const int slot = ((jb >> 3) & 7) ^ (orow & 7);
      *(u16x4*)(Tt + orow*128 + slot*16 + (jb & 7)*2) = c4;
    }
  }
  __syncthreads();

  {
    const int o = tid & 63, c = tid >> 6;
    u16x8 val = *(const u16x8*)(Tt + o*128 + ((c ^ (o & 7)) << 4));
    *(u16x8*)((char*)hpz2 + ((size_t)(bh1*256 + (jbase >> 3) + c)*64 + o)*16) = val;
  }
  if (tid < 64){
    // log2-domain pre-scale; NO max subtraction needed downstream (bounded
    // inputs: |s|,|d| <= ~28.1 in log2 units -> exp2 range fp32-safe)
    srcv[(size_t)bh1*NSEQ + jbase + tid] = (psumS[tid*2] + psumS[tid*2 + 1]) * LOG2E;
    dstv[(size_t)bh1*NSEQ + jbase + tid] = (psumD[tid*2] + psumD[tid*2 + 1]) * LOG2E;
  }
}

// ---------------------------------------------------------------------------
// Kernel B v3: barrier-free direct-global loop + dstv REGISTER PREFETCH.
// Round-3 version loaded d0..d3 at iter top and consumed them immediately,
// exposing L1/L2 latency in the exp2 critical path every iteration. Now both
// the hpz2 fragments AND the dstv vectors are double-buffered one iter ahead.
// ---------------------------------------------------------------------------
__global__ __launch_bounds__(512, 4) void k_attn(
    const unsigned short* __restrict__ hpz2, const float* __restrict__ srcv,
    const float* __restrict__ dstv, const float* __restrict__ bias,
    float* __restrict__ out)
{
  __shared__ __align__(16) char smem[33792];   // ob@0 (32 KB), Lbuf@32768
  float* Lbuf = (float*)(smem + 32768);        // [8][32]

  const int tid = threadIdx.x;
  const int bid = blockIdx.x;
  const int bh  = (bid & 7) | (((bid >> 3) & 1) << 3);
  const int i0  = (bid >> 4) << 6;
  const int wave = tid >> 6, lane = tid & 63;
  const int wm = wave & 1, jw = wave >> 1;
  const int l32 = lane & 31, h32 = lane >> 5;

  const float s2 = srcv[(size_t)bh*NSEQ + i0 + wm*32 + l32];
  const float u_ = s2;                 // lrelu(s+d) = max(u_+d, 0.2d+v_)
  const float v_ = 0.2f*s2;

  // direct-global B fragments: unit(w,Jl,half,l32) = w*1024 + Jl*64 + half*32 + l32
  const u16x8* gp = (const u16x8*)((const char*)hpz2 + (size_t)bh*256*64*16);
  const u16x8* tp = gp + ((jw*4 + h32)*64 + l32);      // Jl0 row; Jl1 = +128
  const float* dS = dstv + (size_t)bh*NSEQ + (jw*4 + h32)*8;  // Jl0 j-chunk; Jl1 = +16

  f32x16 accO0 = {0,0,0,0,0,0,0,0,0,0,0,0,0,0,0,0};
  f32x16 accO1 = {0,0,0,0,0,0,0,0,0,0,0,0,0,0,0,0};
  float lpart = 0.f;

  u16x8 c0 = tp[0], c1 = tp[32], c2 = tp[128], c3 = tp[160];
  float4 d0 = *(const float4*)(dS);
  float4 d1 = *(const float4*)(dS + 4);
  float4 d2 = *(const float4*)(dS + 16);
  float4 d3 = *(const float4*)(dS + 20);

  for (int w = 0; w < 16; ++w){
    u16x8 n0, n1, n2, n3;
    float4 g0, g1, g2, g3;
    if (w < 15){
      const u16x8* np = tp + 1024;
      n0 = np[0]; n1 = np[32]; n2 = np[128]; n3 = np[160];
      const float* dN = dS + 128;
      g0 = *(const float4*)(dN);
      g1 = *(const float4*)(dN + 4);
      g2 = *(const float4*)(dN + 16);
      g3 = *(const float4*)(dN + 20);
    }
    // stl0 (rows jw*4 + h32)
    {
      float e0 = fexp2(fmaxf(u_ + d0.x, fmaf(0.2f, d0.x, v_)));
      float e1 = fexp2(fmaxf(u_ + d0.y, fmaf(0.2f, d0.y, v_)));
      float e2 = fexp2(fmaxf(u_ + d0.z, fmaf(0.2f, d0.z, v_)));
      float e3 = fexp2(fmaxf(u_ + d0.w, fmaf(0.2f, d0.w, v_)));
      float e4 = fexp2(fmaxf(u_ + d1.x, fmaf(0.2f, d1.x, v_)));
      float e5 = fexp2(fmaxf(u_ + d1.y, fmaf(0.2f, d1.y, v_)));
      float e6 = fexp2(fmaxf(u_ + d1.z, fmaf(0.2f, d1.z, v_)));
      float e7 = fexp2(fmaxf(u_ + d1.w, fmaf(0.2f, d1.w, v_)));
      lpart += ((e0+e1)+(e2+e3)) + ((e4+e5)+(e6+e7));
      u32x4 pk;
      pk[0] = pkbf(e0, e1); pk[1] = pkbf(e2, e3);
      pk[2] = pkbf(e4, e5); pk[3] = pkbf(e6, e7);
      const bf16x8 pA = __builtin_bit_cast(bf16x8, pk);
      accO0 = __builtin_amdgcn_mfma_f32_32x32x16_bf16(pA, c0, accO0, 0, 0, 0);
      accO1 = __builtin_amdgcn_mfma_f32_32x32x16_bf16(pA, c1, accO1, 0, 0, 0);
    }
    // stl1 (rows jw*4 + 2 + h32)
    {
      float e0 = fexp2(fmaxf(u_ + d2.x, fmaf(0.2f, d2.x, v_)));
      float e1 = fexp2(fmaxf(u_ + d2.y, fmaf(0.2f, d2.y, v_)));
      float e2 = fexp2(fmaxf(u_ + d2.z, fmaf(0.2f, d2.z, v_)));
      float e3 = fexp2(fmaxf(u_ + d2.w, fmaf(0.2f, d2.w, v_)));
      float e4 = fexp2(fmaxf(u_ + d3.x, fmaf(0.2f, d3.x, v_)));
      float e5 = fexp2(fmaxf(u_ + d3.y, fmaf(0.2f, d3.y, v_)));
      float e6 = fexp2(fmaxf(u_ + d3.z, fmaf(0.2f, d3.z, v_)));
      float e7 = fexp2(fmaxf(u_ + d3.w, fmaf(0.2f, d3.w, v_)));
      lpart += ((e0+e1)+(e2+e3)) + ((e4+e5)+(e6+e7));
      u32x4 pk;
      pk[0] = pkbf(e0, e1); pk[1] = pkbf(e2, e3);
      pk[2] = pkbf(e4, e5); pk[3] = pkbf(e6, e7);
      const bf16x8 pA = __builtin_bit_cast(bf16x8, pk);
      accO0 = __builtin_amdgcn_mfma_f32_32x32x16_bf16(pA, c2, accO0, 0, 0, 0);
      accO1 = __builtin_amdgcn_mfma_f32_32x32x16_bf16(pA, c3, accO1, 0, 0, 0);
    }
    tp += 1024; dS += 128;
    c0 = n0; c1 = n1; c2 = n2; c3 = n3;
    d0 = g0; d1 = g1; d2 = g2; d3 = g3;
  }

  lpart += __shfl_xor(lpart, 32);
  if (lane < 32) Lbuf[(wm*4 + jw)*32 + l32] = lpart;

  const float4 bia = *(const float4*)(bias + (tid & 15)*4);
  #pragma unroll
  for (int ph = 0; ph < 2; ++ph){
    __syncthreads();
    if (wm == ph){
      float* ob = (float*)smem;            // [jw][m 32][o 64] fp32 = 32 KB
      #pragma unroll
      for (int reg = 0; reg < 16; ++reg){
        const int m = (reg & 3) + 8*(reg >> 2) + 4*h32;
        ob[(jw*32 + m)*64 +      l32] = accO0[reg];
        ob[(jw*32 + m)*64 + 32 + l32] = accO1[reg];
      }
    }
    __syncthreads();
    {
      const int i = tid >> 4, o4 = (tid & 15)*4;
      const float* ob = (const float*)smem;
      float4 v0 = *(const float4*)(ob + (0*32 + i)*64 + o4);
      float4 v1 = *(const float4*)(ob + (1*32 + i)*64 + o4);
      float4 v2 = *(const float4*)(ob + (2*32 + i)*64 + o4);
      float4 v3 = *(const float4*)(ob + (3*32 + i)*64 + o4);
      const float l = Lbuf[(ph*4+0)*32 + i] + Lbuf[(ph*4+1)*32 + i]
                    + Lbuf[(ph*4+2)*32 + i] + Lbuf[(ph*4+3)*32 + i];
      const float r = 1.f / l;
      float4 res;
      res.x = (v0.x + v1.x + v2.x + v3.x)*r + bia.x;
      res.y = (v0.y + v1.y + v2.y + v3.y)*r + bia.y;
      res.z = (v0.z + v1.z + v2.z + v3.z)*r + bia.z;
      res.w = (v0.w + v1.w + v2.w + v3.w)*r + bia.w;
      *(float4*)(out + ((size_t)bh*NSEQ + i0 + ph*32 + i)*64 + o4) = res;
    }
  }
}

// ---------------------------------------------------------------------------
extern "C" void kernel_launch(void* const* d_in, const int* in_sizes, int n_in,
                              void* d_out, int out_size, void* d_ws, size_t ws_size,
                              hipStream_t stream)
{
  const float* h     = (const float*)d_in[0];
  const float* w     = (const float*)d_in[1];
  const float* a_src = (const float*)d_in[2];
  const float* a_dst = (const float*)d_in[3];
  const float* bias  = (const float*)d_in[4];
  float* out = (float*)d_out;

  char* ws = (char*)d_ws;
  unsigned short* hpz2 = (unsigned short*)ws;                 // 4 MB bf16 chunk-linear
  float* srcv = (float*)(ws + (4u<<20));                      // 128 KB (log2-scaled)
  float* dstv = (float*)(ws + (4u<<20) + (128u<<10));         // 128 KB (log2-scaled)

  k_hprime<<<512, 512, 0, stream>>>(h, w, a_src, a_dst, hpz2, srcv, dstv);
  k_attn<<<512, 512, 0, stream>>>(hpz2, srcv, dstv, bias, out);
}